// Round 6
// baseline (97.117 us; speedup 1.0000x reference)
//
#include <hip/hip_runtime.h>
#include <hip/hip_bf16.h>

// out[b,s,c] = x[b,s,:] @ W, W[r][c] = kernel[(r%512)*4096 + c]
// Fused design (round 6):
//   Kernel btrans: btq[c][r'] = i8(kernel[r'*4096+c])          (~3 us)
//   Kernel fused : 256 blocks x 512 thr; block owns 32 rows.
//     Phase 1: reduce 8 strided segments of x -> quantize i8 (scale 8)
//              -> LDS A-tile (MFMA-fragment layout). x read ONCE.
//     Phase 2: A-frags in registers; B-frags streamed global->VGPR from
//              L2-resident btq; mfma_i32_16x16x64_i8; per-tile LDS-transpose
//              epilogue -> dense dwordx4 C stores. No barriers in the loop.

#define N_TOT 4096
#define K_RED 512
#define MB    32

typedef __attribute__((ext_vector_type(4))) int   i32x4;
typedef __attribute__((ext_vector_type(4))) float f32x4;

// ---------------------------------------------------------------------------
// btq[c][r'] = i8(kernel[r'*4096 + c])   (transpose, validated in R5)
// ---------------------------------------------------------------------------
__global__ __launch_bounds__(256) void btrans(const int* __restrict__ kin,
                                              char* __restrict__ btq) {
    __shared__ char tile[64][68];
    const int b  = blockIdx.x;               // 0..511
    const int c0 = (b & 63) * 64;
    const int r0 = (b >> 6) * 64;
    const int tx = threadIdx.x & 63;
    const int ty = threadIdx.x >> 6;         // 0..3
#pragma unroll
    for (int rr = 0; rr < 64; rr += 4) {
        int r = r0 + rr + ty;
        tile[rr + ty][tx] = (char)kin[(size_t)r * N_TOT + c0 + tx];
    }
    __syncthreads();
    const int q  = tx & 15;                  // r'-quad (r' = q*4+j)
    const int ch = tx >> 4;                  // 0..3
#pragma unroll
    for (int i = 0; i < 4; ++i) {
        const int cl = i * 16 + ty * 4 + ch; // column offset 0..63
        int p = (tile[q * 4 + 0][cl] & 0xFF)
              | ((tile[q * 4 + 1][cl] & 0xFF) << 8)
              | ((tile[q * 4 + 2][cl] & 0xFF) << 16)
              | ((tile[q * 4 + 3][cl] & 0xFF) << 24);
        *reinterpret_cast<int*>(btq + (size_t)(c0 + cl) * K_RED + r0 + q * 4) = p;
    }
}

// ---------------------------------------------------------------------------
// Fused reduce+quantize+GEMM. Block b: rows m0=b*32 .. m0+31, all 4096 cols.
// ---------------------------------------------------------------------------
__global__ __launch_bounds__(512, 2) void fused(const float* __restrict__ x,
                                                const char* __restrict__ btq,
                                                float* __restrict__ C) {
    // A-tile: addr = ks*2048 + lhi*512 + row32*16 + pos  (k = ks*64+lhi*16+pos)
    __shared__ char  aq[16384];
    __shared__ float ep[8][16][68];          // per-wave epilogue transpose

    const int tid  = threadIdx.x;
    const int lane = tid & 63;
    const int w    = tid >> 6;               // wave 0..7 -> n-stripe
    const int l15  = lane & 15;
    const int lhi  = lane >> 4;              // 0..3
    const int m0   = blockIdx.x * MB;

    // ---- Phase 1: reduce + quantize 32 rows into aq ----
    {
        const int row = tid >> 4;            // 0..31
        const int q   = tid & 15;            // 0..15
        const float* xp = x + (size_t)(m0 + row) * 4096 + q * 4;
        float4 s[8] = {};
#pragma unroll
        for (int seg = 0; seg < 8; ++seg) {
#pragma unroll
            for (int j = 0; j < 8; ++j) {
                float4 v = *reinterpret_cast<const float4*>(xp + seg * 512 + j * 64);
                s[j].x += v.x; s[j].y += v.y; s[j].z += v.z; s[j].w += v.w;
            }
        }
#pragma unroll
        for (int j = 0; j < 8; ++j) {        // r' = j*64 + q*4 + e
            int q0 = min(127, max(-127, (int)rintf(s[j].x * 8.f)));
            int q1 = min(127, max(-127, (int)rintf(s[j].y * 8.f)));
            int q2 = min(127, max(-127, (int)rintf(s[j].z * 8.f)));
            int q3 = min(127, max(-127, (int)rintf(s[j].w * 8.f)));
            int p = (q0 & 0xFF) | ((q1 & 0xFF) << 8) | ((q2 & 0xFF) << 16)
                  | ((q3 & 0xFF) << 24);
            *reinterpret_cast<int*>(aq + j * 2048 + (q >> 2) * 512
                                       + row * 16 + (q & 3) * 4) = p;
        }
    }
    __syncthreads();                         // the only barrier

    // ---- A-fragments into registers (shared by whole wave) ----
    i32x4 af[2][8];
#pragma unroll
    for (int h = 0; h < 2; ++h)
#pragma unroll
        for (int ks = 0; ks < 8; ++ks)
            af[h][ks] = *reinterpret_cast<const i32x4*>(
                aq + ks * 2048 + lhi * 512 + (h * 16 + l15) * 16);

    const int nb = w * 512;                  // wave's n-stripe base

    // ---- Phase 2: n-loop, no barriers ----
    for (int nt = 0; nt < 8; ++nt) {
        i32x4 acc[2][4] = {};
#pragma unroll
        for (int nf = 0; nf < 4; ++nf) {
            const char* bp = btq + (size_t)(nb + nt * 64 + nf * 16 + l15) * K_RED
                                 + lhi * 16;
            i32x4 b8[8];
#pragma unroll
            for (int ks = 0; ks < 8; ++ks)
                b8[ks] = *reinterpret_cast<const i32x4*>(bp + ks * 64);
#pragma unroll
            for (int ks = 0; ks < 8; ++ks) {
                acc[0][nf] = __builtin_amdgcn_mfma_i32_16x16x64_i8(
                    af[0][ks], b8[ks], acc[0][nf], 0, 0, 0);
                acc[1][nf] = __builtin_amdgcn_mfma_i32_16x16x64_i8(
                    af[1][ks], b8[ks], acc[1][nf], 0, 0, 0);
            }
        }
        // epilogue: LDS transpose -> dense dwordx4 stores (scale 1/8)
#pragma unroll
        for (int h = 0; h < 2; ++h) {
#pragma unroll
            for (int nf = 0; nf < 4; ++nf)
#pragma unroll
                for (int r = 0; r < 4; ++r)
                    ep[w][lhi * 4 + r][nf * 16 + l15] =
                        (float)acc[h][nf][r] * 0.125f;
            asm volatile("s_waitcnt lgkmcnt(0)" ::: "memory");
#pragma unroll
            for (int jj = 0; jj < 4; ++jj) {
                const int rowl = jj * 4 + lhi;
                f32x4 v = *reinterpret_cast<const f32x4*>(&ep[w][rowl][l15 * 4]);
                *reinterpret_cast<f32x4*>(
                    &C[(size_t)(m0 + h * 16 + rowl) * N_TOT
                       + nb + nt * 64 + l15 * 4]) = v;
            }
            asm volatile("s_waitcnt lgkmcnt(0)" ::: "memory");
        }
    }
}

// ---------------------------------------------------------------------------
extern "C" void kernel_launch(void* const* d_in, const int* in_sizes, int n_in,
                              void* d_out, int out_size, void* d_ws, size_t ws_size,
                              hipStream_t stream) {
    const float* x   = (const float*)d_in[0];   // [2,4096,4096] f32
    const int*   kin = (const int*)d_in[1];     // [2097152] int32 in {-1,0,1}
    float*       out = (float*)d_out;           // [2,4096,4096] f32

    char* btq = (char*)d_ws;                    // 2 MB

    btrans<<<dim3(512), 256, 0, stream>>>(kin, btq);
    fused<<<dim3(256), 512, 0, stream>>>(x, btq, out);
}